// Round 4
// baseline (508.940 us; speedup 1.0000x reference)
//
#include <hip/hip_runtime.h>

#define EPS 1e-10f
#define FAR_DELTA 1e10f

// Native clang vector so __builtin_nontemporal_load accepts the pointer.
typedef float f4 __attribute__((ext_vector_type(4)));

// DPP move within 16-lane rows: out-of-bounds source lanes yield `old`.
// CTRL: row_shl:N = 0x100+N, row_shr:N = 0x110+N, row_ror:N = 0x120+N.
template<int CTRL>
__device__ __forceinline__ float dpp_mov(float x, float old) {
    return __int_as_float(__builtin_amdgcn_update_dpp(
        __float_as_int(old), __float_as_int(x), CTRL, 0xF, 0xF, false));
}

// Single-touch streaming data: bypass L1 allocation.
__device__ __forceinline__ f4 ntload(const float* p) {
    return __builtin_nontemporal_load((const f4*)p);
}

// One ray per 16-lane group (4 rays per wave). Persistent pipelined waves at
// FULL occupancy: 2048 blocks x 4 waves = 8 waves/SIMD (the HW cap, VGPR<=64),
// each 16-lane group walks 4 rays with the next ray's 10 dwordx4 loads issued
// before computing the current ray -> every SIMD slot keeps a steady stream of
// outstanding line-misses (memcpy-like), instead of bursty one-shot waves
// (r0, 77% occ) or steady-but-half-empty SIMDs (r2, 34% occ).
// All cross-lane traffic is DPP row ops (VALU-speed, no LDS pipe).
__global__ __launch_bounds__(256, 8) void volrend_kernel(
    const float* __restrict__ density,   // [N,128]
    const float* __restrict__ feature,   // [N,128,3]
    const float* __restrict__ depth,     // [N,128]
    float* __restrict__ feat_out,        // [N,3]
    float* __restrict__ depth_out,       // [N]
    int N)
{
    const int tid  = threadIdx.x;
    const int lane = tid & 63;
    const int wv   = tid >> 6;        // wave within block (0..3)
    const int j    = lane & 15;       // sublane within ray group
    const int sub  = lane >> 4;       // ray slot within wave (0..3)
    int ray = blockIdx.x * 16 + wv * 4 + sub;
    const int gstride = gridDim.x * 16;
    if (ray >= N) return;

    // ---- Prologue: load first ray (nontemporal: single-touch stream). ----
    const float* dp = density + (size_t)ray * 128 + j * 8;
    const float* zp = depth   + (size_t)ray * 128 + j * 8;
    const float* fp = feature + (size_t)ray * 384 + j * 24;
    f4 dA = ntload(dp), dB = ntload(dp + 4);
    f4 zA = ntload(zp), zB = ntload(zp + 4);
    f4 F0 = ntload(fp),      F1 = ntload(fp + 4),  F2 = ntload(fp + 8);
    f4 F3 = ntload(fp + 12), F4 = ntload(fp + 16), F5 = ntload(fp + 20);

    while (true) {
        const int nray = ray + gstride;
        const bool have_next = (nray < N);

        // ---- Issue next-ray loads FIRST (hidden under current compute). ----
        f4 ndA, ndB, nzA, nzB, nF0, nF1, nF2, nF3, nF4, nF5;
        if (have_next) {
            const float* ndp = density + (size_t)nray * 128 + j * 8;
            const float* nzp = depth   + (size_t)nray * 128 + j * 8;
            const float* nfp = feature + (size_t)nray * 384 + j * 24;
            ndA = ntload(ndp); ndB = ntload(ndp + 4);
            nzA = ntload(nzp); nzB = ntload(nzp + 4);
            nF0 = ntload(nfp);      nF1 = ntload(nfp + 4);  nF2 = ntload(nfp + 8);
            nF3 = ntload(nfp + 12); nF4 = ntload(nfp + 16); nF5 = ntload(nfp + 20);
        }

        // ---- Compute current ray. ----
        float z[8]  = {zA.x, zA.y, zA.z, zA.w, zB.x, zB.y, zB.z, zB.w};
        float dn[8] = {dA.x, dA.y, dA.z, dA.w, dB.x, dB.y, dB.z, dB.w};

        float znext = dpp_mov<0x101>(z[0], 0.0f);   // row_shl:1 (seam depth)

        float al[8], tt[8];
        #pragma unroll
        for (int k = 0; k < 8; ++k) {
            float delta = (k < 7) ? (z[k + 1] - z[k])
                                  : ((j == 15) ? FAR_DELTA : (znext - z[7]));
            float ex = __expf(-fmaxf(dn[k], 0.0f) * delta); // = 1 - alpha
            al[k] = 1.0f - ex;          // alpha
            tt[k] = ex + EPS;           // cumprod term
        }

        float loc = tt[0];
        #pragma unroll
        for (int k = 1; k < 8; ++k) loc *= tt[k];

        // Width-16 inclusive product scan, pure DPP.
        float s = loc;
        s *= dpp_mov<0x111>(s, 1.0f);   // row_shr:1
        s *= dpp_mov<0x112>(s, 1.0f);   // row_shr:2
        s *= dpp_mov<0x114>(s, 1.0f);   // row_shr:4
        s *= dpp_mov<0x118>(s, 1.0f);   // row_shr:8
        float excl = dpp_mov<0x111>(s, 1.0f);  // exclusive; lane0 -> 1.0

        float f[24] = {F0.x, F0.y, F0.z, F0.w, F1.x, F1.y, F1.z, F1.w,
                       F2.x, F2.y, F2.z, F2.w, F3.x, F3.y, F3.z, F3.w,
                       F4.x, F4.y, F4.z, F4.w, F5.x, F5.y, F5.z, F5.w};

        float trans = excl;
        float a0 = 0.0f, a1 = 0.0f, a2 = 0.0f, ad = 0.0f;
        #pragma unroll
        for (int k = 0; k < 8; ++k) {
            float wk = al[k] * trans;
            trans *= tt[k];
            a0 += wk * f[3 * k + 0];
            a1 += wk * f[3 * k + 1];
            a2 += wk * f[3 * k + 2];
            ad += wk * z[k];
        }

        // Width-16 sum reduction via row rotations (4 parallel chains).
        a0 += dpp_mov<0x128>(a0, 0.0f);  // ror:8
        a1 += dpp_mov<0x128>(a1, 0.0f);
        a2 += dpp_mov<0x128>(a2, 0.0f);
        ad += dpp_mov<0x128>(ad, 0.0f);
        a0 += dpp_mov<0x124>(a0, 0.0f);  // ror:4
        a1 += dpp_mov<0x124>(a1, 0.0f);
        a2 += dpp_mov<0x124>(a2, 0.0f);
        ad += dpp_mov<0x124>(ad, 0.0f);
        a0 += dpp_mov<0x122>(a0, 0.0f);  // ror:2
        a1 += dpp_mov<0x122>(a1, 0.0f);
        a2 += dpp_mov<0x122>(a2, 0.0f);
        ad += dpp_mov<0x122>(ad, 0.0f);
        a0 += dpp_mov<0x121>(a0, 0.0f);  // ror:1
        a1 += dpp_mov<0x121>(a1, 0.0f);
        a2 += dpp_mov<0x121>(a2, 0.0f);
        ad += dpp_mov<0x121>(ad, 0.0f);

        if (j == 0) {
            feat_out[(size_t)ray * 3 + 0] = a0;
            feat_out[(size_t)ray * 3 + 1] = a1;
            feat_out[(size_t)ray * 3 + 2] = a2;
            depth_out[ray] = ad;
        }

        if (!have_next) break;
        ray = nray;
        dA = ndA; dB = ndB; zA = nzA; zB = nzB;
        F0 = nF0; F1 = nF1; F2 = nF2; F3 = nF3; F4 = nF4; F5 = nF5;
    }
}

extern "C" void kernel_launch(void* const* d_in, const int* in_sizes, int n_in,
                              void* d_out, int out_size, void* d_ws, size_t ws_size,
                              hipStream_t stream) {
    const float* density = (const float*)d_in[0];   // [N,128]
    const float* feature = (const float*)d_in[1];   // [N,128,3]
    const float* depth   = (const float*)d_in[2];   // [N,128]

    const int P = 128;
    const int N = in_sizes[0] / P;                  // 131072

    float* feat_out  = (float*)d_out;                 // [N,3]
    float* depth_out = (float*)d_out + (size_t)N * 3; // [N]

    // 2048 blocks x 4 waves = 8192 waves = 8 waves/SIMD (full residency at
    // VGPR<=64). Each 16-lane group walks N/(2048*16) = 4 rays, 1-deep
    // prefetch pipeline -> steady outstanding reads on every SIMD slot.
    int groups_needed = (N + 15) / 16;
    int grid = groups_needed < 2048 ? groups_needed : 2048;
    dim3 block(256);
    volrend_kernel<<<dim3(grid), block, 0, stream>>>(density, feature, depth,
                                                     feat_out, depth_out, N);
}

// Round 5
// 353.564 us; speedup vs baseline: 1.4395x; 1.4395x over previous
//
#include <hip/hip_runtime.h>

#define EPS 1e-10f
#define FAR_DELTA 1e10f

typedef float f4v __attribute__((ext_vector_type(4)));

// DPP move within 16-lane rows: out-of-bounds source lanes yield `old`.
// row_shl:1 (0x101) verified empirically (r1): out[j] = in[j+1], j==15 -> old.
// row_shr:N = 0x110+N (scan), row_ror:N = 0x120+N (direction-agnostic reduce).
template<int CTRL>
__device__ __forceinline__ float dpp_mov(float x, float old) {
    return __int_as_float(__builtin_amdgcn_update_dpp(
        __float_as_int(old), __float_as_int(x), CTRL, 0xF, 0xF, false));
}

// One ray per 16-lane group, 4 rays (one "quad") per wave, one-shot waves.
// KEY CHANGE vs r0-r2: every global load instruction covers CONTIGUOUS fully-
// used cache lines (the old layout issued ~3.2x amplified line-requests:
// density/depth touched each line twice, features read 16B of every 96B).
//  - density/depth: lane j owns samples 4j..4j+3 (lo) and 64+4j..64+4j+3 (hi);
//    the two dwordx4 loads per array are byte-contiguous per 16-lane group.
//  - features: the wave's 4-ray 6KB block is staged to LDS with 6 contiguous
//    wave-wide float4 copies, then ds_read_b128 per-sample slices
//    (wave-private LDS -> no __syncthreads needed).
__global__ __launch_bounds__(256) void volrend_kernel(
    const float* __restrict__ density,   // [N,128]
    const float* __restrict__ feature,   // [N,128,3]
    const float* __restrict__ depth,     // [N,128]
    float* __restrict__ feat_out,        // [N,3]
    float* __restrict__ depth_out,       // [N]
    int N)
{
    __shared__ float lds[4 * 1536];      // 4 waves x 6KB feature block

    const int tid  = threadIdx.x;
    const int lane = tid & 63;
    const int wv   = tid >> 6;           // wave within block (0..3)
    const int j    = lane & 15;          // sublane within ray group
    const int sub  = lane >> 4;          // ray slot within wave (0..3)
    const int ray0 = blockIdx.x * 16 + wv * 4;   // first ray of this wave
    const int ray  = ray0 + sub;
    if (ray >= N) return;

    // ---- density/depth: contiguous split loads (4 lo + 4 hi samples). ----
    const float* dp = density + (size_t)ray * 128;
    const float* zp = depth   + (size_t)ray * 128;
    f4v dA = *(const f4v*)(dp + j * 4);        // samples 4j..4j+3
    f4v dB = *(const f4v*)(dp + 64 + j * 4);   // samples 64+4j..64+4j+3
    f4v zA = *(const f4v*)(zp + j * 4);
    f4v zB = *(const f4v*)(zp + 64 + j * 4);

    // ---- Stage features: 6KB contiguous per wave, fully coalesced. ----
    const float* fsrc = feature + (size_t)ray0 * 384;
    float* flds = lds + wv * 1536;
    f4v FR0 = *(const f4v*)(fsrc + 0 * 256 + lane * 4);
    f4v FR1 = *(const f4v*)(fsrc + 1 * 256 + lane * 4);
    f4v FR2 = *(const f4v*)(fsrc + 2 * 256 + lane * 4);
    f4v FR3 = *(const f4v*)(fsrc + 3 * 256 + lane * 4);
    f4v FR4 = *(const f4v*)(fsrc + 4 * 256 + lane * 4);
    f4v FR5 = *(const f4v*)(fsrc + 5 * 256 + lane * 4);
    *(f4v*)(flds + 0 * 256 + lane * 4) = FR0;
    *(f4v*)(flds + 1 * 256 + lane * 4) = FR1;
    *(f4v*)(flds + 2 * 256 + lane * 4) = FR2;
    *(f4v*)(flds + 3 * 256 + lane * 4) = FR3;
    *(f4v*)(flds + 4 * 256 + lane * 4) = FR4;
    *(f4v*)(flds + 5 * 256 + lane * 4) = FR5;

    // ---- alpha / cumprod terms (while ds_writes drain). ----
    float zlo[4] = {zA.x, zA.y, zA.z, zA.w};
    float zhi[4] = {zB.x, zB.y, zB.z, zB.w};
    float nlo[4] = {dA.x, dA.y, dA.z, dA.w};
    float nhi[4] = {dB.x, dB.y, dB.z, dB.w};

    float znlo = dpp_mov<0x101>(zlo[0], 0.0f);   // lane j+1's zlo[0]
    float znhi = dpp_mov<0x101>(zhi[0], 0.0f);   // lane j+1's zhi[0]
    float z64  = __shfl(zhi[0], 0, 16);          // group lane0's zhi[0] (sample 64)

    float allo[4], ttlo[4], alhi[4], tthi[4];
    #pragma unroll
    for (int k = 0; k < 4; ++k) {
        float dz = (k < 3) ? (zlo[k + 1] - zlo[k])
                           : (((j == 15) ? z64 : znlo) - zlo[3]);
        float ex = __expf(-fmaxf(nlo[k], 0.0f) * dz);
        allo[k] = 1.0f - ex;
        ttlo[k] = ex + EPS;
    }
    #pragma unroll
    for (int k = 0; k < 4; ++k) {
        float dz = (k < 3) ? (zhi[k + 1] - zhi[k])
                           : ((j == 15) ? FAR_DELTA : (znhi - zhi[3]));
        float ex = __expf(-fmaxf(nhi[k], 0.0f) * dz);
        alhi[k] = 1.0f - ex;
        tthi[k] = ex + EPS;
    }

    float plo = ttlo[0] * ttlo[1] * ttlo[2] * ttlo[3];
    float phi = tthi[0] * tthi[1] * tthi[2] * tthi[3];

    // Width-16 inclusive product scans (DPP), then exclusive shifts.
    float slo = plo;
    slo *= dpp_mov<0x111>(slo, 1.0f);
    slo *= dpp_mov<0x112>(slo, 1.0f);
    slo *= dpp_mov<0x114>(slo, 1.0f);
    slo *= dpp_mov<0x118>(slo, 1.0f);
    float exlo = dpp_mov<0x111>(slo, 1.0f);      // lane0 -> 1.0

    float shi = phi;
    shi *= dpp_mov<0x111>(shi, 1.0f);
    shi *= dpp_mov<0x112>(shi, 1.0f);
    shi *= dpp_mov<0x114>(shi, 1.0f);
    shi *= dpp_mov<0x118>(shi, 1.0f);
    float exhi_l = dpp_mov<0x111>(shi, 1.0f);

    float Tlo  = __shfl(slo, 15, 16);            // total lo product (samples 0..63)
    float exhi = Tlo * exhi_l;

    // ---- Features from LDS: per-sample 12-float slices (3x b128 each). ----
    const float* fl = flds + sub * 384 + j * 12;
    f4v g0 = *(const f4v*)(fl + 0);
    f4v g1 = *(const f4v*)(fl + 4);
    f4v g2 = *(const f4v*)(fl + 8);
    f4v h0 = *(const f4v*)(fl + 192);
    f4v h1 = *(const f4v*)(fl + 196);
    f4v h2 = *(const f4v*)(fl + 200);

    // ---- Weights + accumulate (all channel indices compile-time). ----
    float a0 = 0.0f, a1 = 0.0f, a2 = 0.0f, ad = 0.0f;
    {
        float t = exlo;
        float w0 = allo[0] * t; t *= ttlo[0];
        float w1 = allo[1] * t; t *= ttlo[1];
        float w2 = allo[2] * t; t *= ttlo[2];
        float w3 = allo[3] * t;
        a0 += w0 * g0.x; a1 += w0 * g0.y; a2 += w0 * g0.z;
        a0 += w1 * g0.w; a1 += w1 * g1.x; a2 += w1 * g1.y;
        a0 += w2 * g1.z; a1 += w2 * g1.w; a2 += w2 * g2.x;
        a0 += w3 * g2.y; a1 += w3 * g2.z; a2 += w3 * g2.w;
        ad += w0 * zlo[0] + w1 * zlo[1] + w2 * zlo[2] + w3 * zlo[3];
    }
    {
        float t = exhi;
        float w0 = alhi[0] * t; t *= tthi[0];
        float w1 = alhi[1] * t; t *= tthi[1];
        float w2 = alhi[2] * t; t *= tthi[2];
        float w3 = alhi[3] * t;
        a0 += w0 * h0.x; a1 += w0 * h0.y; a2 += w0 * h0.z;
        a0 += w1 * h0.w; a1 += w1 * h1.x; a2 += w1 * h1.y;
        a0 += w2 * h1.z; a1 += w2 * h1.w; a2 += w2 * h2.x;
        a0 += w3 * h2.y; a1 += w3 * h2.z; a2 += w3 * h2.w;
        ad += w0 * zhi[0] + w1 * zhi[1] + w2 * zhi[2] + w3 * zhi[3];
    }

    // Width-16 sum reduction via row rotations (4 parallel VALU chains).
    a0 += dpp_mov<0x128>(a0, 0.0f);  // ror:8
    a1 += dpp_mov<0x128>(a1, 0.0f);
    a2 += dpp_mov<0x128>(a2, 0.0f);
    ad += dpp_mov<0x128>(ad, 0.0f);
    a0 += dpp_mov<0x124>(a0, 0.0f);  // ror:4
    a1 += dpp_mov<0x124>(a1, 0.0f);
    a2 += dpp_mov<0x124>(a2, 0.0f);
    ad += dpp_mov<0x124>(ad, 0.0f);
    a0 += dpp_mov<0x122>(a0, 0.0f);  // ror:2
    a1 += dpp_mov<0x122>(a1, 0.0f);
    a2 += dpp_mov<0x122>(a2, 0.0f);
    ad += dpp_mov<0x122>(ad, 0.0f);
    a0 += dpp_mov<0x121>(a0, 0.0f);  // ror:1
    a1 += dpp_mov<0x121>(a1, 0.0f);
    a2 += dpp_mov<0x121>(a2, 0.0f);
    ad += dpp_mov<0x121>(ad, 0.0f);

    if (j == 0) {
        feat_out[(size_t)ray * 3 + 0] = a0;
        feat_out[(size_t)ray * 3 + 1] = a1;
        feat_out[(size_t)ray * 3 + 2] = a2;
        depth_out[ray] = ad;
    }
}

extern "C" void kernel_launch(void* const* d_in, const int* in_sizes, int n_in,
                              void* d_out, int out_size, void* d_ws, size_t ws_size,
                              hipStream_t stream) {
    const float* density = (const float*)d_in[0];   // [N,128]
    const float* feature = (const float*)d_in[1];   // [N,128,3]
    const float* depth   = (const float*)d_in[2];   // [N,128]

    const int P = 128;
    const int N = in_sizes[0] / P;                  // 131072

    float* feat_out  = (float*)d_out;                 // [N,3]
    float* depth_out = (float*)d_out + (size_t)N * 3; // [N]

    // 16 rays per block (4 waves x 4 rays), one-shot waves.
    dim3 grid((N + 15) / 16);
    dim3 block(256);
    volrend_kernel<<<grid, block, 0, stream>>>(density, feature, depth,
                                               feat_out, depth_out, N);
}

// Round 6
// 352.409 us; speedup vs baseline: 1.4442x; 1.0033x over previous
//
#include <hip/hip_runtime.h>

#define EPS 1e-10f
#define FAR_DELTA 1e10f

typedef float f4v __attribute__((ext_vector_type(4)));

// DPP move within 16-lane rows: out-of-bounds source lanes yield `old`.
// row_shl:1 = 0x101, row_shr:N = 0x110+N, row_ror:N = 0x120+N.
template<int CTRL>
__device__ __forceinline__ float dpp_mov(float x, float old) {
    return __int_as_float(__builtin_amdgcn_update_dpp(
        __float_as_int(old), __float_as_int(x), CTRL, 0xF, 0xF, false));
}

// One ray per 16-lane group, 4 rays per wave, one-shot waves, r5's fully
// coalesced layout. NEW: an asm register fence pins ALL 10 global dwordx4
// loads in flight simultaneously before any use. Previous rounds (VGPR=32..52)
// show the allocator sinking loads into waitcnt-gated batches of ~2-3 ->
// ~40 outstanding lines/CU -> 2.9 TB/s latency-bound ceiling. The fence
// forces 10 loads/wave outstanding (160 lines) with ONE vmcnt wait.
__global__ __launch_bounds__(256) void volrend_kernel(
    const float* __restrict__ density,   // [N,128]
    const float* __restrict__ feature,   // [N,128,3]
    const float* __restrict__ depth,     // [N,128]
    float* __restrict__ feat_out,        // [N,3]
    float* __restrict__ depth_out,       // [N]
    int N)
{
    __shared__ float lds[4 * 1536];      // 4 waves x 6KB feature block

    const int tid  = threadIdx.x;
    const int lane = tid & 63;
    const int wv   = tid >> 6;           // wave within block (0..3)
    const int j    = lane & 15;          // sublane within ray group
    const int sub  = lane >> 4;          // ray slot within wave (0..3)
    const int ray0 = blockIdx.x * 16 + wv * 4;   // first ray of this wave
    const int ray  = ray0 + sub;
    if (ray >= N) return;

    // ---- Issue ALL 10 global loads (fully coalesced, contiguous lines). ----
    const float* dp   = density + (size_t)ray * 128;
    const float* zp   = depth   + (size_t)ray * 128;
    const float* fsrc = feature + (size_t)ray0 * 384;

    f4v dA = *(const f4v*)(dp + j * 4);        // samples 4j..4j+3
    f4v dB = *(const f4v*)(dp + 64 + j * 4);   // samples 64+4j..
    f4v zA = *(const f4v*)(zp + j * 4);
    f4v zB = *(const f4v*)(zp + 64 + j * 4);
    f4v FR0 = *(const f4v*)(fsrc + 0 * 256 + lane * 4);
    f4v FR1 = *(const f4v*)(fsrc + 1 * 256 + lane * 4);
    f4v FR2 = *(const f4v*)(fsrc + 2 * 256 + lane * 4);
    f4v FR3 = *(const f4v*)(fsrc + 3 * 256 + lane * 4);
    f4v FR4 = *(const f4v*)(fsrc + 4 * 256 + lane * 4);
    f4v FR5 = *(const f4v*)(fsrc + 5 * 256 + lane * 4);

    // ---- MLP fence: every load result is an asm operand, so no load can be
    // sunk past this point; compiler emits ONE s_waitcnt here with all 10
    // dwordx4 (160 cache lines per wave) in flight.
    asm volatile("" : "+v"(dA), "+v"(dB), "+v"(zA), "+v"(zB),
                      "+v"(FR0), "+v"(FR1), "+v"(FR2), "+v"(FR3),
                      "+v"(FR4), "+v"(FR5));

    // ---- Stage features to LDS (wave-private block, no barrier needed). ----
    float* flds = lds + wv * 1536;
    *(f4v*)(flds + 0 * 256 + lane * 4) = FR0;
    *(f4v*)(flds + 1 * 256 + lane * 4) = FR1;
    *(f4v*)(flds + 2 * 256 + lane * 4) = FR2;
    *(f4v*)(flds + 3 * 256 + lane * 4) = FR3;
    *(f4v*)(flds + 4 * 256 + lane * 4) = FR4;
    *(f4v*)(flds + 5 * 256 + lane * 4) = FR5;

    // ---- alpha / cumprod terms (while ds_writes drain). ----
    float zlo[4] = {zA.x, zA.y, zA.z, zA.w};
    float zhi[4] = {zB.x, zB.y, zB.z, zB.w};
    float nlo[4] = {dA.x, dA.y, dA.z, dA.w};
    float nhi[4] = {dB.x, dB.y, dB.z, dB.w};

    float znlo = dpp_mov<0x101>(zlo[0], 0.0f);   // lane j+1's zlo[0]
    float znhi = dpp_mov<0x101>(zhi[0], 0.0f);   // lane j+1's zhi[0]
    float z64  = __shfl(zhi[0], 0, 16);          // group lane0's zhi[0]

    float allo[4], ttlo[4], alhi[4], tthi[4];
    #pragma unroll
    for (int k = 0; k < 4; ++k) {
        float dz = (k < 3) ? (zlo[k + 1] - zlo[k])
                           : (((j == 15) ? z64 : znlo) - zlo[3]);
        float ex = __expf(-fmaxf(nlo[k], 0.0f) * dz);
        allo[k] = 1.0f - ex;
        ttlo[k] = ex + EPS;
    }
    #pragma unroll
    for (int k = 0; k < 4; ++k) {
        float dz = (k < 3) ? (zhi[k + 1] - zhi[k])
                           : ((j == 15) ? FAR_DELTA : (znhi - zhi[3]));
        float ex = __expf(-fmaxf(nhi[k], 0.0f) * dz);
        alhi[k] = 1.0f - ex;
        tthi[k] = ex + EPS;
    }

    float plo = ttlo[0] * ttlo[1] * ttlo[2] * ttlo[3];
    float phi = tthi[0] * tthi[1] * tthi[2] * tthi[3];

    // Width-16 inclusive product scans (DPP), then exclusive shifts.
    float slo = plo;
    slo *= dpp_mov<0x111>(slo, 1.0f);
    slo *= dpp_mov<0x112>(slo, 1.0f);
    slo *= dpp_mov<0x114>(slo, 1.0f);
    slo *= dpp_mov<0x118>(slo, 1.0f);
    float exlo = dpp_mov<0x111>(slo, 1.0f);      // lane0 -> 1.0

    float shi = phi;
    shi *= dpp_mov<0x111>(shi, 1.0f);
    shi *= dpp_mov<0x112>(shi, 1.0f);
    shi *= dpp_mov<0x114>(shi, 1.0f);
    shi *= dpp_mov<0x118>(shi, 1.0f);
    float exhi_l = dpp_mov<0x111>(shi, 1.0f);

    float Tlo  = __shfl(slo, 15, 16);            // total lo product
    float exhi = Tlo * exhi_l;

    // ---- Features from LDS: per-sample 12-float slices (3x b128 each). ----
    const float* fl = flds + sub * 384 + j * 12;
    f4v g0 = *(const f4v*)(fl + 0);
    f4v g1 = *(const f4v*)(fl + 4);
    f4v g2 = *(const f4v*)(fl + 8);
    f4v h0 = *(const f4v*)(fl + 192);
    f4v h1 = *(const f4v*)(fl + 196);
    f4v h2 = *(const f4v*)(fl + 200);

    // ---- Weights + accumulate (all channel indices compile-time). ----
    float a0 = 0.0f, a1 = 0.0f, a2 = 0.0f, ad = 0.0f;
    {
        float t = exlo;
        float w0 = allo[0] * t; t *= ttlo[0];
        float w1 = allo[1] * t; t *= ttlo[1];
        float w2 = allo[2] * t; t *= ttlo[2];
        float w3 = allo[3] * t;
        a0 += w0 * g0.x; a1 += w0 * g0.y; a2 += w0 * g0.z;
        a0 += w1 * g0.w; a1 += w1 * g1.x; a2 += w1 * g1.y;
        a0 += w2 * g1.z; a1 += w2 * g1.w; a2 += w2 * g2.x;
        a0 += w3 * g2.y; a1 += w3 * g2.z; a2 += w3 * g2.w;
        ad += w0 * zlo[0] + w1 * zlo[1] + w2 * zlo[2] + w3 * zlo[3];
    }
    {
        float t = exhi;
        float w0 = alhi[0] * t; t *= tthi[0];
        float w1 = alhi[1] * t; t *= tthi[1];
        float w2 = alhi[2] * t; t *= tthi[2];
        float w3 = alhi[3] * t;
        a0 += w0 * h0.x; a1 += w0 * h0.y; a2 += w0 * h0.z;
        a0 += w1 * h0.w; a1 += w1 * h1.x; a2 += w1 * h1.y;
        a0 += w2 * h1.z; a1 += w2 * h1.w; a2 += w2 * h2.x;
        a0 += w3 * h2.y; a1 += w3 * h2.z; a2 += w3 * h2.w;
        ad += w0 * zhi[0] + w1 * zhi[1] + w2 * zhi[2] + w3 * zhi[3];
    }

    // Width-16 sum reduction via row rotations (4 parallel VALU chains).
    a0 += dpp_mov<0x128>(a0, 0.0f);  // ror:8
    a1 += dpp_mov<0x128>(a1, 0.0f);
    a2 += dpp_mov<0x128>(a2, 0.0f);
    ad += dpp_mov<0x128>(ad, 0.0f);
    a0 += dpp_mov<0x124>(a0, 0.0f);  // ror:4
    a1 += dpp_mov<0x124>(a1, 0.0f);
    a2 += dpp_mov<0x124>(a2, 0.0f);
    ad += dpp_mov<0x124>(ad, 0.0f);
    a0 += dpp_mov<0x122>(a0, 0.0f);  // ror:2
    a1 += dpp_mov<0x122>(a1, 0.0f);
    a2 += dpp_mov<0x122>(a2, 0.0f);
    ad += dpp_mov<0x122>(ad, 0.0f);
    a0 += dpp_mov<0x121>(a0, 0.0f);  // ror:1
    a1 += dpp_mov<0x121>(a1, 0.0f);
    a2 += dpp_mov<0x121>(a2, 0.0f);
    ad += dpp_mov<0x121>(ad, 0.0f);

    if (j == 0) {
        feat_out[(size_t)ray * 3 + 0] = a0;
        feat_out[(size_t)ray * 3 + 1] = a1;
        feat_out[(size_t)ray * 3 + 2] = a2;
        depth_out[ray] = ad;
    }
}

extern "C" void kernel_launch(void* const* d_in, const int* in_sizes, int n_in,
                              void* d_out, int out_size, void* d_ws, size_t ws_size,
                              hipStream_t stream) {
    const float* density = (const float*)d_in[0];   // [N,128]
    const float* feature = (const float*)d_in[1];   // [N,128,3]
    const float* depth   = (const float*)d_in[2];   // [N,128]

    const int P = 128;
    const int N = in_sizes[0] / P;                  // 131072

    float* feat_out  = (float*)d_out;                 // [N,3]
    float* depth_out = (float*)d_out + (size_t)N * 3; // [N]

    // 16 rays per block (4 waves x 4 rays), one-shot waves.
    dim3 grid((N + 15) / 16);
    dim3 block(256);
    volrend_kernel<<<grid, block, 0, stream>>>(density, feature, depth,
                                               feat_out, depth_out, N);
}